// Round 2
// baseline (594.903 us; speedup 1.0000x reference)
//
#include <hip/hip_runtime.h>
#include <hip/hip_bf16.h>

typedef __hip_bfloat16 bf16;

#define HW 4096

__device__ __forceinline__ float b2f(bf16 x) { return __bfloat162float(x); }
__device__ __forceinline__ bf16 f2b(float x) { return __float2bfloat16(x); }

__device__ __forceinline__ float cvt(float x) { return x; }
__device__ __forceinline__ float cvt(bf16 x) { return b2f(x); }
__device__ __forceinline__ void stv(float* p, float v) { *p = v; }
__device__ __forceinline__ void stv(bf16* p, float v) { *p = f2b(v); }

// ---------------------------------------------------------------------------
// Tiled GEMM: Out[b,o,n] = sum_c X[b,c,n] * Wm[o,c]   (+ optional BN epilogue)
// Tile 64(o) x 64(n) x 16(k), 256 threads, 4x4 micro-tile per thread.
// ---------------------------------------------------------------------------
template <int M, int K, bool FUSE_BN, typename TIN, typename TOUT>
__global__ __launch_bounds__(256) void gemm_bn_kernel(
    const TIN* __restrict__ X,    // [B, K, HW]
    const float* __restrict__ Wm, // [M, K]
    TOUT* __restrict__ Out,       // [B, M, HW]
    const float* __restrict__ bng, const float* __restrict__ bnb,
    const float* __restrict__ bnm, const float* __restrict__ bnv) {
  __shared__ float sX[16][64];
  __shared__ float sW[16][65];
  const int b = blockIdx.z;
  const int ob = blockIdx.y * 64;
  const int nb = blockIdx.x * 64;
  const int tid = threadIdx.x;
  const int tx = tid & 15, ty = tid >> 4;
  const TIN* Xb = X + (size_t)b * K * HW;
  float acc[4][4] = {};
  for (int k0 = 0; k0 < K; k0 += 16) {
#pragma unroll
    for (int r = 0; r < 4; ++r) {
      int idx = r * 256 + tid;
      int kk = idx >> 6, nn = idx & 63;
      sX[kk][nn] = cvt(Xb[(size_t)(k0 + kk) * HW + nb + nn]);
      int oo = idx >> 4, k2 = idx & 15;
      sW[k2][oo] = Wm[(size_t)(ob + oo) * K + k0 + k2];
    }
    __syncthreads();
#pragma unroll
    for (int kk = 0; kk < 16; ++kk) {
      float ax[4], aw[4];
#pragma unroll
      for (int j = 0; j < 4; ++j) ax[j] = sX[kk][tx * 4 + j];
#pragma unroll
      for (int i = 0; i < 4; ++i) aw[i] = sW[kk][ty * 4 + i];
#pragma unroll
      for (int i = 0; i < 4; ++i)
#pragma unroll
        for (int j = 0; j < 4; ++j) acc[i][j] = fmaf(aw[i], ax[j], acc[i][j]);
    }
    __syncthreads();
  }
#pragma unroll
  for (int i = 0; i < 4; ++i) {
    int o = ob + ty * 4 + i;
    float scale = 1.f, shift = 0.f;
    if (FUSE_BN) {
      float g = bng[o], be = bnb[o];
      float mu = bnm[o], va = bnv[o];
      scale = g * rsqrtf(va + 1e-5f);
      shift = be - mu * scale;
    }
    TOUT* orow = Out + ((size_t)b * M + o) * HW + nb + tx * 4;
#pragma unroll
    for (int j = 0; j < 4; ++j) {
      float v = acc[i][j];
      if (FUSE_BN) v = v * scale + shift;
      stv(orow + j, v);
    }
  }
}

// ---------------------------------------------------------------------------
// Fused depthwise 5x5 conv + grouped pointwise (8->8 per group).
// One block per (b, group, 8-row h-tile). dw values live only in registers.
// ---------------------------------------------------------------------------
__global__ __launch_bounds__(256) void dwpw_kernel(
    const bf16* __restrict__ qkv,   // [B, 768, HW]
    const float* __restrict__ wdw,  // [768, 25]
    const float* __restrict__ wpw,  // [96, 8, 8]
    bf16* __restrict__ pw) {        // [B, 768, HW]
  __shared__ float sT[8][12][68];
  __shared__ float sWd[8][25];
  __shared__ float sWp[8][8];
  const int b = blockIdx.z;
  const int g = blockIdx.y;
  const int h0 = blockIdx.x * 8;
  const int tid = threadIdx.x;
  for (int i = tid; i < 200; i += 256)
    sWd[i / 25][i % 25] = wdw[(g * 8 + i / 25) * 25 + i % 25];
  if (tid < 64) sWp[tid >> 3][tid & 7] = wpw[g * 64 + tid];
  const bf16* qb = qkv + ((size_t)b * 768 + g * 8) * HW;
  for (int idx = tid; idx < 8 * 12 * 68; idx += 256) {
    int ci = idx / (12 * 68);
    int rem = idx % (12 * 68);
    int rr = rem / 68, cc = rem % 68;
    int h = h0 + rr - 2, w = cc - 2;
    float v = 0.f;
    if (h >= 0 && h < 64 && w >= 0 && w < 64) v = b2f(qb[(size_t)ci * HW + h * 64 + w]);
    sT[ci][rr][cc] = v;
  }
  __syncthreads();
  const int tw = tid & 63, th = tid >> 6;
#pragma unroll
  for (int rep = 0; rep < 2; ++rep) {
    int rl = th + rep * 4;
    float dwv[8];
#pragma unroll
    for (int ci = 0; ci < 8; ++ci) {
      float a = 0.f;
#pragma unroll
      for (int dy = 0; dy < 5; ++dy)
#pragma unroll
        for (int dx = 0; dx < 5; ++dx)
          a = fmaf(sT[ci][rl + dy][tw + dx], sWd[ci][dy * 5 + dx], a);
      dwv[ci] = a;
    }
    bf16* ob = pw + ((size_t)b * 768 + g * 8) * HW + (h0 + rl) * 64 + tw;
#pragma unroll
    for (int o = 0; o < 8; ++o) {
      float a = 0.f;
#pragma unroll
      for (int i = 0; i < 8; ++i) a = fmaf(sWp[o][i], dwv[i], a);
      ob[(size_t)o * HW] = f2b(a);
    }
  }
}

// ---------------------------------------------------------------------------
// ReLU linear attention. One block per (b, head). ms = concat(qkv, pw) on
// channel axis; head h uses channels [24h, 24h+24): q=0..7, k=8..15, v=16..23.
// kv[d][e] = sum_n relu(k_d) * v_e  (v_8 == 1);  out = (q . kv) normalized.
// ---------------------------------------------------------------------------
__global__ __launch_bounds__(256) void attn_kernel(
    const bf16* __restrict__ qkv,  // [B, 768, HW]
    const bf16* __restrict__ pw,   // [B, 768, HW]
    bf16* __restrict__ att) {      // [B, 512, HW]
  const int bh = blockIdx.x;
  const int b = bh >> 6, h = bh & 63;
  const bf16* src = (h < 32) ? qkv + ((size_t)b * 768 + 24 * h) * HW
                             : pw + ((size_t)b * 768 + 24 * h - 768) * HW;
  const int tid = threadIdx.x;
  float kv[72] = {};  // kv[d*9+e]
  for (int n = tid; n < HW; n += 256) {
    float kd[8], ve[8];
#pragma unroll
    for (int d = 0; d < 8; ++d) kd[d] = fmaxf(b2f(src[(size_t)(8 + d) * HW + n]), 0.f);
#pragma unroll
    for (int e = 0; e < 8; ++e) ve[e] = b2f(src[(size_t)(16 + e) * HW + n]);
#pragma unroll
    for (int d = 0; d < 8; ++d) {
#pragma unroll
      for (int e = 0; e < 8; ++e) kv[d * 9 + e] = fmaf(kd[d], ve[e], kv[d * 9 + e]);
      kv[d * 9 + 8] += kd[d];
    }
  }
  __shared__ float sRed[4][72];
  __shared__ float sKV[72];
  const int lane = tid & 63, wave = tid >> 6;
#pragma unroll
  for (int t = 0; t < 72; ++t) {
    float v = kv[t];
    v += __shfl_down(v, 32);
    v += __shfl_down(v, 16);
    v += __shfl_down(v, 8);
    v += __shfl_down(v, 4);
    v += __shfl_down(v, 2);
    v += __shfl_down(v, 1);
    if (lane == 0) sRed[wave][t] = v;
  }
  __syncthreads();
  if (tid < 72) sKV[tid] = sRed[0][tid] + sRed[1][tid] + sRed[2][tid] + sRed[3][tid];
  __syncthreads();
  float kvf[72];
#pragma unroll
  for (int t = 0; t < 72; ++t) kvf[t] = sKV[t];
  bf16* ob = att + ((size_t)b * 512 + h * 8) * HW;
  for (int n = tid; n < HW; n += 256) {
    float qd[8];
#pragma unroll
    for (int d = 0; d < 8; ++d) qd[d] = fmaxf(b2f(src[(size_t)d * HW + n]), 0.f);
    float o[9] = {};
#pragma unroll
    for (int d = 0; d < 8; ++d)
#pragma unroll
      for (int e = 0; e < 9; ++e) o[e] = fmaf(qd[d], kvf[d * 9 + e], o[e]);
    float rinv = 1.0f / (o[8] + 1e-15f);
#pragma unroll
    for (int e = 0; e < 8; ++e) ob[(size_t)e * HW + n] = f2b(o[e] * rinv);
  }
}

// ---------------------------------------------------------------------------
extern "C" void kernel_launch(void* const* d_in, const int* in_sizes, int n_in,
                              void* d_out, int out_size, void* d_ws, size_t ws_size,
                              hipStream_t stream) {
  const float* x = (const float*)d_in[0];       // [8,256,64,64]
  const float* w_qkv = (const float*)d_in[1];   // [768,256]
  const float* w_dw = (const float*)d_in[2];    // [768,1,5,5]
  const float* w_pw = (const float*)d_in[3];    // [96,8,8]
  const float* w_proj = (const float*)d_in[4];  // [256,512]
  const float* bng = (const float*)d_in[5];
  const float* bnb = (const float*)d_in[6];
  const float* bnm = (const float*)d_in[7];
  const float* bnv = (const float*)d_in[8];
  float* out = (float*)d_out;  // [8,256,64,64]

  bf16* qkv = (bf16*)d_ws;                     // 8*768*4096 bf16 = 48 MiB
  bf16* pw = qkv + (size_t)8 * 768 * HW;       // 48 MiB
  bf16* att = pw + (size_t)8 * 768 * HW;       // 32 MiB

  // 1) qkv = x @ w_qkv^T   (M=768, K=256)
  gemm_bn_kernel<768, 256, false, float, bf16><<<dim3(64, 12, 8), 256, 0, stream>>>(
      x, w_qkv, qkv, nullptr, nullptr, nullptr, nullptr);
  // 2) pw = grouped_pointwise(depthwise5x5(qkv))
  dwpw_kernel<<<dim3(8, 96, 8), 256, 0, stream>>>(qkv, w_dw, w_pw, pw);
  // 3) att = relu_linear_attention(concat(qkv, pw))
  attn_kernel<<<dim3(512), 256, 0, stream>>>(qkv, pw, att);
  // 4) out = BN(att @ w_proj^T)   (M=256, K=512)
  gemm_bn_kernel<256, 512, true, bf16, float><<<dim3(64, 4, 8), 256, 0, stream>>>(
      att, w_proj, out, bng, bnb, bnm, bnv);
}